// Round 5
// baseline (1658.086 us; speedup 1.0000x reference)
//
#include <hip/hip_runtime.h>

// HashEncoder forward: B=1e6 points, D=3, L=16, C=2, H=16, T=2^19.
// R4 restructure: thread = POINT (1M threads), 16 levels swept sequentially
// in-thread. Rationale (from R3 counters: FETCH=5.0GB, dur=1446us, 45% HBM):
// the old (point,level)-per-thread layout made every wave touch all 13
// hashed 4MB tables at once -> 52MB random working set vs 4MB L2/XCD ->
// ~40% L2 hit, 8x line over-fetch. Sequential level sweep keeps all resident
// waves on ~2 adjacent levels (~8MB active) -> table lines reused ~100x
// while L2-hot.
//
//  - Full unroll: level constants (res, off, dense-vs-hash) fold at compile
//    time; no divergence; o[] indexing stays register-allocated (rule #20).
//  - 8 corner gathers issued per level before any FMA (one vmcnt window).
//  - Output: 32 floats in regs -> 8 NT float4 stores; each lane fully
//    writes its own two 64B lines (no partial-line write amplification);
//    NT so the write-once 128MB stream doesn't evict the tables from L2/L3.

#define P1 2654435761u
#define P2 805459861u
#define HASH_MASK ((1u << 19) - 1u)

typedef float f32x2 __attribute__((ext_vector_type(2)));
typedef float f32x4 __attribute__((ext_vector_type(4)));

__global__ __launch_bounds__(256) void hashenc_kernel(
    const float* __restrict__ inputs,   // [B,3]
    const float* __restrict__ emb,      // [7131219, 2]
    float* __restrict__ out,            // [B, 32]
    int B)
{
    const int b = blockIdx.x * 256 + threadIdx.x;
    if (b >= B) return;

    float vx = inputs[b * 3 + 0];
    float vy = inputs[b * 3 + 1];
    float vz = inputs[b * 3 + 2];

    // normalize to [0,1]: clip((v+1)*0.5, 0, 1)
    vx = fminf(fmaxf((vx + 1.0f) * 0.5f, 0.0f), 1.0f);
    vy = fminf(fmaxf((vy + 1.0f) * 0.5f, 0.0f), 1.0f);
    vz = fminf(fmaxf((vz + 1.0f) * 0.5f, 0.0f), 1.0f);

    const f32x2* __restrict__ e2 = (const f32x2*)emb;

    float o[32];

#pragma unroll
    for (int l = 0; l < 16; ++l) {
        const float resf = (float)(16 << l);

        float px = vx * resf, py = vy * resf, pz = vz * resf;
        // pos >= 0 always, so only the upper clip is needed on floor(pos).
        float gx = fminf(floorf(px), resf - 1.0f);
        float gy = fminf(floorf(py), resf - 1.0f);
        float gz = fminf(floorf(pz), resf - 1.0f);
        float fx = px - gx, fy = py - gy, fz = pz - gz;

        unsigned int cx = (unsigned int)gx;
        unsigned int cy = (unsigned int)gy;
        unsigned int cz = (unsigned int)gz;

        // Per-level base offset (compile-time after unroll).
        // Dense: 17^3=4913, +33^3=40850, +65^3=315475; hashed: +2^19 each.
        const unsigned int off =
            (l == 0) ? 0u :
            (l == 1) ? 4913u :
            (l == 2) ? 40850u :
                       315475u + (unsigned int)(l - 3) * 524288u;

        // Corner indices. combo bit2 -> x, bit1 -> y, bit0 -> z.
        unsigned int idx[8];
        if (l >= 3) {
            // spatial hash: x ^ (y*P1) ^ (z*P2), uint32 wrap, & (2^19-1)
            unsigned int x1  = cx + 1u;
            unsigned int yp0 = cy * P1;
            unsigned int yp1 = yp0 + P1;
            unsigned int zp0 = cz * P2;
            unsigned int zp1 = zp0 + P2;
            idx[0] = (cx ^ yp0 ^ zp0) & HASH_MASK;
            idx[1] = (cx ^ yp0 ^ zp1) & HASH_MASK;
            idx[2] = (cx ^ yp1 ^ zp0) & HASH_MASK;
            idx[3] = (cx ^ yp1 ^ zp1) & HASH_MASK;
            idx[4] = (x1 ^ yp0 ^ zp0) & HASH_MASK;
            idx[5] = (x1 ^ yp0 ^ zp1) & HASH_MASK;
            idx[6] = (x1 ^ yp1 ^ zp0) & HASH_MASK;
            idx[7] = (x1 ^ yp1 ^ zp1) & HASH_MASK;
        } else {
            // dense: x + y*(res+1) + z*(res+1)^2, always < size (no mod)
            unsigned int s1 = (unsigned int)resf + 1u;
            unsigned int s2 = s1 * s1;
            unsigned int base = cx + cy * s1 + cz * s2;
            idx[0] = base;
            idx[1] = base + s2;
            idx[2] = base + s1;
            idx[3] = base + s1 + s2;
            idx[4] = base + 1u;
            idx[5] = base + 1u + s2;
            idx[6] = base + 1u + s1;
            idx[7] = base + 1u + s1 + s2;
        }

        // Issue all 8 gathers before consuming (latency batching).
        f32x2 f[8];
#pragma unroll
        for (int k = 0; k < 8; ++k) f[k] = e2[off + idx[k]];

        // Trilinear weights: w[k] = wx[bit2] * wy[bit1] * wz[bit0]
        float a0 = 1.0f - fx, a1 = fx;
        float u0 = 1.0f - fy, u1 = fy;
        float txy[4] = {a0 * u0, a0 * u1, a1 * u0, a1 * u1};
        float vv[2]  = {1.0f - fz, fz};

        float acc0 = 0.0f, acc1 = 0.0f;
#pragma unroll
        for (int k = 0; k < 8; ++k) {
            float w = txy[k >> 1] * vv[k & 1];
            acc0 = fmaf(w, f[k].x, acc0);
            acc1 = fmaf(w, f[k].y, acc1);
        }

        o[2 * l]     = acc0;   // compile-time index -> stays in VGPRs
        o[2 * l + 1] = acc1;
    }

    // Write-once output: 8 full float4 stores, non-temporal.
    f32x4* o4 = (f32x4*)(out + (size_t)b * 32);
#pragma unroll
    for (int i = 0; i < 8; ++i) {
        f32x4 v;
        v.x = o[4 * i]; v.y = o[4 * i + 1]; v.z = o[4 * i + 2]; v.w = o[4 * i + 3];
        __builtin_nontemporal_store(v, o4 + i);
    }
}

extern "C" void kernel_launch(void* const* d_in, const int* in_sizes, int n_in,
                              void* d_out, int out_size, void* d_ws, size_t ws_size,
                              hipStream_t stream) {
    const float* inputs = (const float*)d_in[0];
    const float* emb    = (const float*)d_in[1];
    float* out          = (float*)d_out;

    int B = in_sizes[0] / 3;
    int block = 256;
    int grid = (B + block - 1) / block;
    hashenc_kernel<<<grid, block, 0, stream>>>(inputs, emb, out, B);
}

// Round 7
// 704.444 us; speedup vs baseline: 2.3538x; 2.3538x over previous
//
#include <hip/hip_runtime.h>

// HashEncoder forward: B=1e6, D=3, L=16, C=2, H=16, T=2^19.
//
// R5 structure (from R3/R4 counters: FETCH ~5.3GB both rounds => all-levels-
// live working set (52MB) thrashes the 4MB/XCD L2; in-thread level sweep
// drifts and doesn't phase):
//   Kernel 1 (phase): grid (3907, 16), blockIdx.y = level (slowest-varying
//     in dispatch order). All resident blocks process the SAME level =>
//     one 4MB table resident per XCD L2 => gathers ~L2-hit after first touch.
//     Writes level-major scratch ws[l][b] (f32x2, wave-contiguous, NT full
//     lines). R4 lesson: NT + strided partial lines = 2.6x write blowup, so
//     never NT a partial-line pattern.
//   Kernel 2 (transpose): LDS tile 16 levels x 128 points -> out[b][32],
//     coalesced NT reads/writes both sides.
// Fallback: if ws_size < B*16*8 bytes, phase kernel writes out directly
// (strided, slower but correct).

#define P1 2654435761u
#define P2 805459861u
#define HASH_MASK ((1u << 19) - 1u)

typedef float f32x2 __attribute__((ext_vector_type(2)));
typedef float f32x4 __attribute__((ext_vector_type(4)));

__global__ __launch_bounds__(256) void hashenc_phase(
    const float* __restrict__ inputs,   // [B,3]
    const float* __restrict__ emb,      // [7131219,2]
    f32x2* __restrict__ ws,             // [16,B] level-major scratch (or null)
    float* __restrict__ out,            // [B,32] (used only if direct)
    int B, int direct)
{
    const int l = blockIdx.y;                    // level 0..15 (block-uniform)
    const int b = blockIdx.x * 256 + threadIdx.x;
    if (b >= B) return;

    float vx = inputs[b * 3 + 0];
    float vy = inputs[b * 3 + 1];
    float vz = inputs[b * 3 + 2];

    // normalize to [0,1]: clip((v+1)*0.5, 0, 1)
    vx = fminf(fmaxf((vx + 1.0f) * 0.5f, 0.0f), 1.0f);
    vy = fminf(fmaxf((vy + 1.0f) * 0.5f, 0.0f), 1.0f);
    vz = fminf(fmaxf((vz + 1.0f) * 0.5f, 0.0f), 1.0f);

    const float resf = (float)(16 << l);

    float px = vx * resf, py = vy * resf, pz = vz * resf;
    float gx = fminf(floorf(px), resf - 1.0f);   // pos >= 0, only upper clip
    float gy = fminf(floorf(py), resf - 1.0f);
    float gz = fminf(floorf(pz), resf - 1.0f);
    float fx = px - gx, fy = py - gy, fz = pz - gz;

    unsigned int cx = (unsigned int)gx;
    unsigned int cy = (unsigned int)gy;
    unsigned int cz = (unsigned int)gz;

    // Per-level base offset. Dense: 17^3=4913, +33^3=40850, +65^3=315475;
    // hashed levels add 2^19 each. Scalar (l is block-uniform).
    unsigned int off;
    if (l == 0)      off = 0u;
    else if (l == 1) off = 4913u;
    else if (l == 2) off = 40850u;
    else             off = 315475u + (unsigned int)(l - 3) * 524288u;

    // Corner indices. combo bit2 -> x, bit1 -> y, bit0 -> z.
    // Branch is wave-uniform (l uniform across block).
    unsigned int idx[8];
    if (l >= 3) {
        unsigned int x1  = cx + 1u;
        unsigned int yp0 = cy * P1;
        unsigned int yp1 = yp0 + P1;
        unsigned int zp0 = cz * P2;
        unsigned int zp1 = zp0 + P2;
        idx[0] = (cx ^ yp0 ^ zp0) & HASH_MASK;
        idx[1] = (cx ^ yp0 ^ zp1) & HASH_MASK;
        idx[2] = (cx ^ yp1 ^ zp0) & HASH_MASK;
        idx[3] = (cx ^ yp1 ^ zp1) & HASH_MASK;
        idx[4] = (x1 ^ yp0 ^ zp0) & HASH_MASK;
        idx[5] = (x1 ^ yp0 ^ zp1) & HASH_MASK;
        idx[6] = (x1 ^ yp1 ^ zp0) & HASH_MASK;
        idx[7] = (x1 ^ yp1 ^ zp1) & HASH_MASK;
    } else {
        unsigned int s1 = (unsigned int)resf + 1u;
        unsigned int s2 = s1 * s1;
        unsigned int base = cx + cy * s1 + cz * s2;
        idx[0] = base;
        idx[1] = base + s2;
        idx[2] = base + s1;
        idx[3] = base + s1 + s2;
        idx[4] = base + 1u;
        idx[5] = base + 1u + s2;
        idx[6] = base + 1u + s1;
        idx[7] = base + 1u + s1 + s2;
    }

    // Issue all 8 gathers before consuming (one vmcnt window).
    const f32x2* __restrict__ e2 = (const f32x2*)emb;
    f32x2 f[8];
#pragma unroll
    for (int k = 0; k < 8; ++k) f[k] = e2[off + idx[k]];

    // Trilinear weights: w[k] = wx[bit2] * wy[bit1] * wz[bit0]
    float a0 = 1.0f - fx, a1 = fx;
    float u0 = 1.0f - fy, u1 = fy;
    float txy[4] = {a0 * u0, a0 * u1, a1 * u0, a1 * u1};
    float vv[2]  = {1.0f - fz, fz};

    float acc0 = 0.0f, acc1 = 0.0f;
#pragma unroll
    for (int k = 0; k < 8; ++k) {
        float w = txy[k >> 1] * vv[k & 1];
        acc0 = fmaf(w, f[k].x, acc0);
        acc1 = fmaf(w, f[k].y, acc1);
    }

    f32x2 r; r.x = acc0; r.y = acc1;
    if (!direct) {
        // Level-major scratch: wave-contiguous (512 B/wave) -> NT full lines.
        __builtin_nontemporal_store(r, ws + (size_t)l * B + b);
    } else {
        // Fallback: strided direct write (partial lines -> keep cached).
        *(f32x2*)(out + (size_t)b * 32 + 2 * l) = r;
    }
}

// Transpose ws[16][B] -> out[B][32]. Block: 256 threads, tile 128 points.
__global__ __launch_bounds__(256) void hashenc_transpose(
    const f32x2* __restrict__ ws, float* __restrict__ out, int B)
{
    // [16][129] f32x2: +1 pad => read-side (stride-l) banks spread.
    __shared__ f32x2 tile[16][129];

    const int tid = threadIdx.x;
    const int p0  = blockIdx.x * 128;

    // Load 16 levels x 128 points, coalesced in b (8 elems/thread).
#pragma unroll
    for (int i = 0; i < 8; ++i) {
        int e = i * 256 + tid;          // 0..2047
        int l = e >> 7;
        int p = e & 127;
        int b = p0 + p;
        if (b < B)
            tile[l][p] = __builtin_nontemporal_load(ws + (size_t)l * B + b);
    }
    __syncthreads();

    // Store 128 points x 32 floats = 16 KB contiguous, as f32x4 (4/thread).
#pragma unroll
    for (int i = 0; i < 4; ++i) {
        int e = i * 256 + tid;          // f32x4 slot 0..1023
        int p = e >> 3;                 // point within tile
        int l0 = (e & 7) * 2;           // first of two levels in this f32x4
        if (p0 + p < B) {
            f32x2 a = tile[l0][p];
            f32x2 c = tile[l0 + 1][p];
            f32x4 v; v.x = a.x; v.y = a.y; v.z = c.x; v.w = c.y;
            __builtin_nontemporal_store(v, (f32x4*)out + (size_t)p0 * 8 + e);
        }
    }
}

extern "C" void kernel_launch(void* const* d_in, const int* in_sizes, int n_in,
                              void* d_out, int out_size, void* d_ws, size_t ws_size,
                              hipStream_t stream) {
    const float* inputs = (const float*)d_in[0];
    const float* emb    = (const float*)d_in[1];
    float* out          = (float*)d_out;

    int B = in_sizes[0] / 3;
    size_t ws_need = (size_t)B * 16 * sizeof(f32x2);
    int direct = (d_ws == nullptr || ws_size < ws_need) ? 1 : 0;
    f32x2* ws = (f32x2*)d_ws;

    dim3 grid((B + 255) / 256, 16);
    hashenc_phase<<<grid, 256, 0, stream>>>(inputs, emb, ws, out, B, direct);

    if (!direct) {
        int tgrid = (B + 127) / 128;
        hashenc_transpose<<<tgrid, 256, 0, stream>>>(ws, out, B);
    }
}

// Round 9
// 571.263 us; speedup vs baseline: 2.9025x; 1.2331x over previous
//
#include <hip/hip_runtime.h>

// HashEncoder forward: B=1e6, D=3, L=16, C=2, H=16, T=2^19.
//
// R7: R5's level-phased structure confirmed by counters (FETCH 5.3GB->540MB).
// Phase kernel at 128M/547us = 0.38 probes/cyc/CU = ~12/cyc/XCD: TCC
// tag-probe throughput wall. Lever: fewer unique-line probes.
// x-prime == 1 so corner pairs (k,k+4) differ by idx^(cx^(cx+1));
// for even cx that is idx^1 = ADJACENT table entries -> one 16B load serves
// both corners (memcpy: table base off may be odd -> only 8B-aligned).
// Halves probe count for ~50% of lanes on hash levels (13/16 of work).
// Transpose: f32x4 global loads (2 points/load) halve load instructions.

#define P1 2654435761u
#define P2 805459861u
#define HASH_MASK ((1u << 19) - 1u)

typedef float f32x2 __attribute__((ext_vector_type(2)));
typedef float f32x4 __attribute__((ext_vector_type(4)));

__global__ __launch_bounds__(256) void hashenc_phase(
    const float* __restrict__ inputs,   // [B,3]
    const float* __restrict__ emb,      // [7131219,2]
    f32x2* __restrict__ ws,             // [16,B] level-major scratch
    float* __restrict__ out,            // [B,32] (only if direct)
    int B, int direct)
{
    const int l = blockIdx.y;                    // level (block-uniform)
    const int b = blockIdx.x * 256 + threadIdx.x;
    if (b >= B) return;

    float vx = inputs[b * 3 + 0];
    float vy = inputs[b * 3 + 1];
    float vz = inputs[b * 3 + 2];

    // normalize to [0,1]: clip((v+1)*0.5, 0, 1)
    vx = fminf(fmaxf((vx + 1.0f) * 0.5f, 0.0f), 1.0f);
    vy = fminf(fmaxf((vy + 1.0f) * 0.5f, 0.0f), 1.0f);
    vz = fminf(fmaxf((vz + 1.0f) * 0.5f, 0.0f), 1.0f);

    const float resf = (float)(16 << l);

    float px = vx * resf, py = vy * resf, pz = vz * resf;
    float gx = fminf(floorf(px), resf - 1.0f);   // pos >= 0, upper clip only
    float gy = fminf(floorf(py), resf - 1.0f);
    float gz = fminf(floorf(pz), resf - 1.0f);
    float fx = px - gx, fy = py - gy, fz = pz - gz;

    unsigned int cx = (unsigned int)gx;
    unsigned int cy = (unsigned int)gy;
    unsigned int cz = (unsigned int)gz;

    // Per-level base offset. Dense: 17^3=4913, +33^3=40850, +65^3=315475;
    // hashed levels add 2^19 each.
    unsigned int off;
    if (l == 0)      off = 0u;
    else if (l == 1) off = 4913u;
    else if (l == 2) off = 40850u;
    else             off = 315475u + (unsigned int)(l - 3) * 524288u;

    const f32x2* __restrict__ e2 = (const f32x2*)emb;
    f32x2 f[8];   // corners: bit2->x, bit1->y, bit0->z; f[k+4] = x+1 of f[k]

    if (l >= 3) {
        // spatial hash: x ^ (y*P1) ^ (z*P2), uint32 wrap, & (2^19-1)
        unsigned int yp0 = cy * P1;
        unsigned int yp1 = yp0 + P1;
        unsigned int zp0 = cz * P2;
        unsigned int zp1 = zp0 + P2;
        unsigned int ia[4];
        ia[0] = (cx ^ yp0 ^ zp0) & HASH_MASK;
        ia[1] = (cx ^ yp0 ^ zp1) & HASH_MASK;
        ia[2] = (cx ^ yp1 ^ zp0) & HASH_MASK;
        ia[3] = (cx ^ yp1 ^ zp1) & HASH_MASK;

        if (!(cx & 1u)) {
            // cx even: idx[k+4] = ia[k]^1 -> pair {ia&~1, ia|1} adjacent.
            // One 16B load serves both corners (8B-aligned: off may be odd).
#pragma unroll
            for (int k = 0; k < 4; ++k) {
                size_t byteoff = ((size_t)off + (ia[k] & ~1u)) * 8u;
                f32x4 v;
                __builtin_memcpy(&v, (const char*)emb + byteoff, 16);
                f32x2 lo, hi;
                lo.x = v.x; lo.y = v.y; hi.x = v.z; hi.y = v.w;
                bool o = (ia[k] & 1u) != 0u;
                f[k]     = o ? hi : lo;
                f[k + 4] = o ? lo : hi;
            }
        } else {
            // cx odd: idx[k+4] = (ia[k] ^ (cx^(cx+1))) & MASK; 8 separate.
            unsigned int xm = cx ^ (cx + 1u);
#pragma unroll
            for (int k = 0; k < 4; ++k) {
                f[k]     = e2[off + ia[k]];
                f[k + 4] = e2[off + ((ia[k] ^ xm) & HASH_MASK)];
            }
        }
    } else {
        // dense: x + y*(res+1) + z*(res+1)^2, always < size (no mod)
        unsigned int s1 = (unsigned int)resf + 1u;
        unsigned int s2 = s1 * s1;
        unsigned int base = cx + cy * s1 + cz * s2;
        unsigned int idx[8] = {base,      base + s2,
                               base + s1, base + s1 + s2,
                               base + 1u,      base + 1u + s2,
                               base + 1u + s1, base + 1u + s1 + s2};
#pragma unroll
        for (int k = 0; k < 8; ++k) f[k] = e2[off + idx[k]];
    }

    // Trilinear weights: w[k] = wx[bit2] * wy[bit1] * wz[bit0]
    float a0 = 1.0f - fx, a1 = fx;
    float u0 = 1.0f - fy, u1 = fy;
    float txy[4] = {a0 * u0, a0 * u1, a1 * u0, a1 * u1};
    float vv[2]  = {1.0f - fz, fz};

    float acc0 = 0.0f, acc1 = 0.0f;
#pragma unroll
    for (int k = 0; k < 8; ++k) {
        float w = txy[k >> 1] * vv[k & 1];
        acc0 = fmaf(w, f[k].x, acc0);
        acc1 = fmaf(w, f[k].y, acc1);
    }

    f32x2 r; r.x = acc0; r.y = acc1;
    if (!direct) {
        // Level-major scratch: wave-contiguous (512B/wave) -> NT full lines.
        __builtin_nontemporal_store(r, ws + (size_t)l * B + b);
    } else {
        // Fallback: strided direct write (partial lines -> keep cached).
        *(f32x2*)(out + (size_t)b * 32 + 2 * l) = r;
    }
}

// Transpose ws[16][B] -> out[B][32]. Block: 256 threads, tile 128 points.
__global__ __launch_bounds__(256) void hashenc_transpose(
    const f32x2* __restrict__ ws, float* __restrict__ out, int B)
{
    // [16][130] f32x2: even pad keeps 16B row alignment for b128 ops,
    // row stride 1040B spreads read-side banks (+4 per row).
    __shared__ f32x2 tile[16][130];

    const int tid = threadIdx.x;
    const int p0  = blockIdx.x * 128;

    // Load 16 levels x 128 points as f32x4 (2 points/load), 4 loads/thread.
#pragma unroll
    for (int i = 0; i < 4; ++i) {
        int e  = i * 256 + tid;        // f32x4 slot 0..1023
        int lv = e >> 6;               // 64 f32x4 per level row
        int p2 = (e & 63) * 2;         // even point pair base
        if (p0 + p2 < B) {             // B even, p2 even -> +1 also < B
            f32x4 v = __builtin_nontemporal_load(
                (const f32x4*)(ws + (size_t)lv * B + p0 + p2));
            f32x2 a; a.x = v.x; a.y = v.y;
            f32x2 c; c.x = v.z; c.y = v.w;
            tile[lv][p2]     = a;
            tile[lv][p2 + 1] = c;
        }
    }
    __syncthreads();

    // Store 128 points x 32 floats = 16KB contiguous, as f32x4 (4/thread).
#pragma unroll
    for (int i = 0; i < 4; ++i) {
        int e  = i * 256 + tid;        // f32x4 slot 0..1023
        int p  = e >> 3;               // point within tile
        int l0 = (e & 7) * 2;          // two levels per f32x4
        if (p0 + p < B) {
            f32x2 a = tile[l0][p];
            f32x2 c = tile[l0 + 1][p];
            f32x4 v; v.x = a.x; v.y = a.y; v.z = c.x; v.w = c.y;
            __builtin_nontemporal_store(v, (f32x4*)out + (size_t)p0 * 8 + e);
        }
    }
}

extern "C" void kernel_launch(void* const* d_in, const int* in_sizes, int n_in,
                              void* d_out, int out_size, void* d_ws, size_t ws_size,
                              hipStream_t stream) {
    const float* inputs = (const float*)d_in[0];
    const float* emb    = (const float*)d_in[1];
    float* out          = (float*)d_out;

    int B = in_sizes[0] / 3;
    size_t ws_need = (size_t)B * 16 * sizeof(f32x2);
    int direct = (d_ws == nullptr || ws_size < ws_need) ? 1 : 0;
    f32x2* ws = (f32x2*)d_ws;

    dim3 grid((B + 255) / 256, 16);
    hashenc_phase<<<grid, 256, 0, stream>>>(inputs, emb, ws, out, B, direct);

    if (!direct) {
        int tgrid = (B + 127) / 128;
        hashenc_transpose<<<tgrid, 256, 0, stream>>>(ws, out, B);
    }
}

// Round 10
// 544.804 us; speedup vs baseline: 3.0435x; 1.0486x over previous
//
#include <hip/hip_runtime.h>

// HashEncoder forward: B=1e6, D=3, L=16, C=2, H=16, T=2^19.
//
// Structure (validated R5/R7 counters): level-phased gather kernel
// (blockIdx.y = level -> one 4MB table per XCD L2; FETCH 5.3GB->0.57GB),
// level-major f32x2 scratch (wave-contiguous NT full-line stores), then
// LDS-transpose kernel -> out[b][32] coalesced NT both sides.
// Phase kernel is TCC probe-throughput bound (~12 probes/cyc/XCD): R7's
// even-cx hash corner-pairing gave the predicted probe-proportional win
// (547->408us). R9: pair dense corners too (x-stride=1 -> idx(x+1)=idx(x)+1
// ALWAYS adjacent, no parity branch), and 256-point transpose tiles.

#define P1 2654435761u
#define P2 805459861u
#define HASH_MASK ((1u << 19) - 1u)

typedef float f32x2 __attribute__((ext_vector_type(2)));
typedef float f32x4 __attribute__((ext_vector_type(4)));

__global__ __launch_bounds__(256) void hashenc_phase(
    const float* __restrict__ inputs,   // [B,3]
    const float* __restrict__ emb,      // [7131219,2]
    f32x2* __restrict__ ws,             // [16,B] level-major scratch
    float* __restrict__ out,            // [B,32] (only if direct)
    int B, int direct)
{
    const int l = blockIdx.y;                    // level (block-uniform)
    const int b = blockIdx.x * 256 + threadIdx.x;
    if (b >= B) return;

    float vx = inputs[b * 3 + 0];
    float vy = inputs[b * 3 + 1];
    float vz = inputs[b * 3 + 2];

    // normalize to [0,1]: clip((v+1)*0.5, 0, 1)
    vx = fminf(fmaxf((vx + 1.0f) * 0.5f, 0.0f), 1.0f);
    vy = fminf(fmaxf((vy + 1.0f) * 0.5f, 0.0f), 1.0f);
    vz = fminf(fmaxf((vz + 1.0f) * 0.5f, 0.0f), 1.0f);

    const float resf = (float)(16 << l);

    float px = vx * resf, py = vy * resf, pz = vz * resf;
    float gx = fminf(floorf(px), resf - 1.0f);   // pos >= 0, upper clip only
    float gy = fminf(floorf(py), resf - 1.0f);
    float gz = fminf(floorf(pz), resf - 1.0f);
    float fx = px - gx, fy = py - gy, fz = pz - gz;

    unsigned int cx = (unsigned int)gx;
    unsigned int cy = (unsigned int)gy;
    unsigned int cz = (unsigned int)gz;

    // Per-level base offset. Dense: 17^3=4913, +33^3=40850, +65^3=315475;
    // hashed levels add 2^19 each.
    unsigned int off;
    if (l == 0)      off = 0u;
    else if (l == 1) off = 4913u;
    else if (l == 2) off = 40850u;
    else             off = 315475u + (unsigned int)(l - 3) * 524288u;

    const f32x2* __restrict__ e2 = (const f32x2*)emb;
    f32x2 f[8];   // corners: bit2->x, bit1->y, bit0->z; f[k+4] = x+1 of f[k]

    if (l >= 3) {
        // spatial hash: x ^ (y*P1) ^ (z*P2), uint32 wrap, & (2^19-1)
        unsigned int yp0 = cy * P1;
        unsigned int yp1 = yp0 + P1;
        unsigned int zp0 = cz * P2;
        unsigned int zp1 = zp0 + P2;
        unsigned int ia[4];
        ia[0] = (cx ^ yp0 ^ zp0) & HASH_MASK;
        ia[1] = (cx ^ yp0 ^ zp1) & HASH_MASK;
        ia[2] = (cx ^ yp1 ^ zp0) & HASH_MASK;
        ia[3] = (cx ^ yp1 ^ zp1) & HASH_MASK;

        if (!(cx & 1u)) {
            // cx even: idx[k+4] = ia[k]^1 -> pair {ia&~1, ia|1} adjacent.
            // One 16B load serves both corners (8B-aligned: off may be odd).
#pragma unroll
            for (int k = 0; k < 4; ++k) {
                size_t byteoff = ((size_t)off + (ia[k] & ~1u)) * 8u;
                f32x4 v;
                __builtin_memcpy(&v, (const char*)emb + byteoff, 16);
                f32x2 lo, hi;
                lo.x = v.x; lo.y = v.y; hi.x = v.z; hi.y = v.w;
                bool o = (ia[k] & 1u) != 0u;
                f[k]     = o ? hi : lo;
                f[k + 4] = o ? lo : hi;
            }
        } else {
            // cx odd: idx[k+4] = (ia[k] ^ (cx^(cx+1))) & MASK; 8 separate.
            unsigned int xm = cx ^ (cx + 1u);
#pragma unroll
            for (int k = 0; k < 4; ++k) {
                f[k]     = e2[off + ia[k]];
                f[k + 4] = e2[off + ((ia[k] ^ xm) & HASH_MASK)];
            }
        }
    } else {
        // dense: x + y*(res+1) + z*(res+1)^2; x-stride = 1 so corners
        // (k, k+4) are ALWAYS adjacent entries -> 4 x 16B loads, no branch.
        unsigned int s1 = (unsigned int)resf + 1u;
        unsigned int s2 = s1 * s1;
        unsigned int base = cx + cy * s1 + cz * s2;
        unsigned int ia[4] = {base, base + s2, base + s1, base + s1 + s2};
#pragma unroll
        for (int k = 0; k < 4; ++k) {
            size_t byteoff = ((size_t)off + ia[k]) * 8u;
            f32x4 v;
            __builtin_memcpy(&v, (const char*)emb + byteoff, 16);
            f32x2 lo, hi;
            lo.x = v.x; lo.y = v.y; hi.x = v.z; hi.y = v.w;
            f[k]     = lo;     // x = cx
            f[k + 4] = hi;     // x = cx+1
        }
    }

    // Trilinear weights: w[k] = wx[bit2] * wy[bit1] * wz[bit0]
    float a0 = 1.0f - fx, a1 = fx;
    float u0 = 1.0f - fy, u1 = fy;
    float txy[4] = {a0 * u0, a0 * u1, a1 * u0, a1 * u1};
    float vv[2]  = {1.0f - fz, fz};

    float acc0 = 0.0f, acc1 = 0.0f;
#pragma unroll
    for (int k = 0; k < 8; ++k) {
        float w = txy[k >> 1] * vv[k & 1];
        acc0 = fmaf(w, f[k].x, acc0);
        acc1 = fmaf(w, f[k].y, acc1);
    }

    f32x2 r; r.x = acc0; r.y = acc1;
    if (!direct) {
        // Level-major scratch: wave-contiguous (512B/wave) -> NT full lines.
        __builtin_nontemporal_store(r, ws + (size_t)l * B + b);
    } else {
        // Fallback: strided direct write (partial lines -> keep cached).
        *(f32x2*)(out + (size_t)b * 32 + 2 * l) = r;
    }
}

// Transpose ws[16][B] -> out[B][32]. Block: 256 threads, tile 256 points.
__global__ __launch_bounds__(256) void hashenc_transpose(
    const f32x2* __restrict__ ws, float* __restrict__ out, int B)
{
    // [16][258] f32x2: even pad keeps 16B row alignment (row 2064B),
    // spreads read-side banks. 33KB LDS -> ~4 blocks/CU.
    __shared__ f32x2 tile[16][258];

    const int tid = threadIdx.x;
    const int p0  = blockIdx.x * 256;

    // Load 16 levels x 256 points as f32x4 (2 points/load), 8 loads/thread.
#pragma unroll
    for (int i = 0; i < 8; ++i) {
        int e  = i * 256 + tid;        // f32x4 slot 0..2047
        int lv = e >> 7;               // 128 f32x4 per level row
        int p2 = (e & 127) * 2;        // even point pair base
        if (p0 + p2 < B) {             // B even, p2 even -> +1 also < B
            f32x4 v = __builtin_nontemporal_load(
                (const f32x4*)(ws + (size_t)lv * B + p0 + p2));
            f32x2 a; a.x = v.x; a.y = v.y;
            f32x2 c; c.x = v.z; c.y = v.w;
            tile[lv][p2]     = a;
            tile[lv][p2 + 1] = c;
        }
    }
    __syncthreads();

    // Store 256 points x 32 floats = 32KB contiguous, as f32x4 (8/thread).
#pragma unroll
    for (int i = 0; i < 8; ++i) {
        int e  = i * 256 + tid;        // f32x4 slot 0..2047
        int p  = e >> 3;               // point within tile
        int l0 = (e & 7) * 2;          // two levels per f32x4
        if (p0 + p < B) {
            f32x2 a = tile[l0][p];
            f32x2 c = tile[l0 + 1][p];
            f32x4 v; v.x = a.x; v.y = a.y; v.z = c.x; v.w = c.y;
            __builtin_nontemporal_store(v, (f32x4*)out + (size_t)p0 * 8 + e);
        }
    }
}

extern "C" void kernel_launch(void* const* d_in, const int* in_sizes, int n_in,
                              void* d_out, int out_size, void* d_ws, size_t ws_size,
                              hipStream_t stream) {
    const float* inputs = (const float*)d_in[0];
    const float* emb    = (const float*)d_in[1];
    float* out          = (float*)d_out;

    int B = in_sizes[0] / 3;
    size_t ws_need = (size_t)B * 16 * sizeof(f32x2);
    int direct = (d_ws == nullptr || ws_size < ws_need) ? 1 : 0;
    f32x2* ws = (f32x2*)d_ws;

    dim3 grid((B + 255) / 256, 16);
    hashenc_phase<<<grid, 256, 0, stream>>>(inputs, emb, ws, out, B, direct);

    if (!direct) {
        int tgrid = (B + 255) / 256;
        hashenc_transpose<<<tgrid, 256, 0, stream>>>(ws, out, B);
    }
}